// Round 3
// baseline (514.396 us; speedup 1.0000x reference)
//
#include <hip/hip_runtime.h>
#include <stdint.h>

typedef __attribute__((ext_vector_type(8))) short s16x8;
typedef __attribute__((ext_vector_type(4))) float f32x4;

__device__ __forceinline__ short f2bf(float x) {
  uint32_t u = __builtin_bit_cast(uint32_t, x);
  u += 0x7FFFu + ((u >> 16) & 1u);  // RNE
  return (short)(u >> 16);
}

__device__ __forceinline__ void gload16(void* l, const void* g) {
  __builtin_amdgcn_global_load_lds(
      (const __attribute__((address_space(1))) void*)g,
      (__attribute__((address_space(3))) void*)l, 16, 0, 0);
}

__device__ __forceinline__ float gelu_tanh(float x) {
  float u = 0.7978845608028654f * (x + 0.044715f * x * x * x);
  float e = __expf(2.0f * u);
  return x - x / (e + 1.0f);
}

// Aq[m][0:1024] = bf16(codebook[idx[m]][:])  -- gather + convert, 2 rows/block
__global__ void gather_cvt(const float* __restrict__ cb, const int* __restrict__ idx,
                           short* __restrict__ out) {
  int m = blockIdx.x * 2 + (threadIdx.x >> 7);
  int c = (threadIdx.x & 127) * 8;
  const float* s = cb + (size_t)idx[m] * 1024 + c;
  s16x8 o;
#pragma unroll
  for (int j = 0; j < 8; ++j) o[j] = f2bf(s[j]);
  *(s16x8*)(out + (size_t)m * 1024 + c) = o;
}

// in [K][N] fp32 -> out [N][K] bf16
__global__ void cvt_T(const float* __restrict__ in, short* __restrict__ out, int K, int N) {
  int Kb = K >> 3;
  int t = blockIdx.x * 256 + threadIdx.x;
  if (t >= N * Kb) return;
  int n = t / Kb;
  int k8 = (t - n * Kb) * 8;
  const float* s = in + (size_t)k8 * N + n;
  s16x8 o;
#pragma unroll
  for (int j = 0; j < 8; ++j) o[j] = f2bf(s[(size_t)j * N]);
  *(s16x8*)(out + (size_t)n * K + k8) = o;
}

// ---------------------------------------------------------------------------
// 4-phase 256xBN x64 bf16 GEMM, 8 waves (2M x 4N), double-buffered LDS,
// counted vmcnt, XOR-swizzled LDS (zero bank conflicts), XCD-chunked
// column-major tile order (B-panel L2 reuse).
// MODE 1: epilogue bias+GELU -> bf16. MODE 2: epilogue bias -> fp32.
// ---------------------------------------------------------------------------
template <int MODE, int K, int N, int BN>
__global__ __launch_bounds__(512, 2) void gemm8p(
    const short* __restrict__ A, const short* __restrict__ Bt,
    const float* __restrict__ bias, void* __restrict__ Cv) {
  constexpr int NIH = BN / 128;        // n-frags per phase-half per wave
  constexpr int RB = BN / 64;          // B staging rounds per K-tile
  constexpr int ATS = 16384;           // A tile shorts (256*64)
  constexpr int LDSH = (256 + BN) * 64;
  __shared__ short lds[2 * LDSH];

  constexpr int NBN = N / BN;
  const int nwg = gridDim.x;
  const int NBM = nwg / NBN;
  int swz = blockIdx.x;
  swz = (swz & 7) * (nwg >> 3) + (swz >> 3);  // XCD swizzle (nwg % 8 == 0)
  const int bn = swz / NBM, bm = swz - bn * NBM;  // column-major: B-panel/XCD reuse

  const int tid = threadIdx.x;
  const int wid = tid >> 6, lane = tid & 63;
  const int wr = wid >> 2, wc = wid & 3;  // per-wave C: 128 x BN/4
  const int lr = lane & 15, hi = lane >> 4;

  // staging: round = 64 rows (8KB); thread -> row (tid>>3), phys slot tid&7,
  // fetch logical slot (tid&7)^(row&7)  (inverse swizzle on the source side)
  const int sl = (tid & 7) ^ ((tid >> 3) & 7);
  const short* aptr[4];
  const short* bptr[RB];
#pragma unroll
  for (int r = 0; r < 4; ++r)
    aptr[r] = A + (long)(bm * 256 + r * 64 + (tid >> 3)) * K + sl * 8;
#pragma unroll
  for (int r = 0; r < RB; ++r)
    bptr[r] = Bt + (long)(bn * BN + r * 64 + (tid >> 3)) * K + sl * 8;
  const int wlds = wid * 512;

  const int aRB = (wr * 128 + lr) * 64;
  const int bRB = ATS + (wc * (BN / 4) + lr) * 64;
  const int sk0 = ((0 + hi) ^ (lr & 7)) * 8;
  const int sk1 = ((4 + hi) ^ (lr & 7)) * 8;

  f32x4 acc[8][2 * NIH] = {};
  s16x8 af[4][2], bf[2][NIH][2];

  constexpr int NT = K >> 6;

  // prologue: tile 0 -> buf0; order B0..B(RB-1), A0, A2, A1, A3
#pragma unroll
  for (int r = 0; r < RB; ++r) gload16(&lds[ATS + r * 4096 + wlds], bptr[r]);
  gload16(&lds[0 * 4096 + wlds], aptr[0]);
  gload16(&lds[2 * 4096 + wlds], aptr[2]);
  gload16(&lds[1 * 4096 + wlds], aptr[1]);
  gload16(&lds[3 * 4096 + wlds], aptr[3]);
  asm volatile("s_waitcnt vmcnt(2)" ::: "memory");
  __builtin_amdgcn_s_barrier();

  for (int t = 0; t < NT; ++t) {
    const int cb = (t & 1) * LDSH;
    const int nb = LDSH - cb;
    const int kt = ((t + 1 < NT) ? (t + 1) : 0) << 6;

    // ---- phase 1: (mh0, nh0); stage next B[0..RB/2) ----
#pragma unroll
    for (int mi = 0; mi < 4; ++mi) {
      af[mi][0] = *(const s16x8*)&lds[cb + aRB + mi * 1024 + sk0];
      af[mi][1] = *(const s16x8*)&lds[cb + aRB + mi * 1024 + sk1];
    }
#pragma unroll
    for (int ni = 0; ni < NIH; ++ni) {
      bf[0][ni][0] = *(const s16x8*)&lds[cb + bRB + ni * 1024 + sk0];
      bf[0][ni][1] = *(const s16x8*)&lds[cb + bRB + ni * 1024 + sk1];
    }
#pragma unroll
    for (int r = 0; r < RB / 2; ++r)
      gload16(&lds[nb + ATS + r * 4096 + wlds], bptr[r] + kt);
    __builtin_amdgcn_s_barrier();
    asm volatile("s_waitcnt lgkmcnt(0)" ::: "memory");
    __builtin_amdgcn_s_setprio(1);
#pragma unroll
    for (int mi = 0; mi < 4; ++mi)
#pragma unroll
      for (int ni = 0; ni < NIH; ++ni)
#pragma unroll
        for (int ks = 0; ks < 2; ++ks)
          acc[mi][ni] = __builtin_amdgcn_mfma_f32_16x16x32_bf16(af[mi][ks], bf[0][ni][ks], acc[mi][ni], 0, 0, 0);
    __builtin_amdgcn_s_setprio(0);
    __builtin_amdgcn_s_barrier();

    // ---- phase 2: (mh0, nh1); stage next B[RB/2..RB); vmcnt(RB) ----
#pragma unroll
    for (int ni = 0; ni < NIH; ++ni) {
      bf[1][ni][0] = *(const s16x8*)&lds[cb + bRB + (NIH + ni) * 1024 + sk0];
      bf[1][ni][1] = *(const s16x8*)&lds[cb + bRB + (NIH + ni) * 1024 + sk1];
    }
#pragma unroll
    for (int r = RB / 2; r < RB; ++r)
      gload16(&lds[nb + ATS + r * 4096 + wlds], bptr[r] + kt);
    __builtin_amdgcn_s_barrier();
    asm volatile("s_waitcnt lgkmcnt(0)" ::: "memory");
    __builtin_amdgcn_s_setprio(1);
#pragma unroll
    for (int mi = 0; mi < 4; ++mi)
#pragma unroll
      for (int ni = 0; ni < NIH; ++ni)
#pragma unroll
        for (int ks = 0; ks < 2; ++ks)
          acc[mi][NIH + ni] = __builtin_amdgcn_mfma_f32_16x16x32_bf16(af[mi][ks], bf[1][ni][ks], acc[mi][NIH + ni], 0, 0, 0);
    __builtin_amdgcn_s_setprio(0);
    if constexpr (RB == 4) asm volatile("s_waitcnt vmcnt(4)" ::: "memory");
    else                   asm volatile("s_waitcnt vmcnt(2)" ::: "memory");
    __builtin_amdgcn_s_barrier();

    // ---- phase 3: (mh1, nh0); stage next A0,A2 ----
#pragma unroll
    for (int mi = 0; mi < 4; ++mi) {
      af[mi][0] = *(const s16x8*)&lds[cb + aRB + 4096 + mi * 1024 + sk0];
      af[mi][1] = *(const s16x8*)&lds[cb + aRB + 4096 + mi * 1024 + sk1];
    }
    gload16(&lds[nb + 0 * 4096 + wlds], aptr[0] + kt);
    gload16(&lds[nb + 2 * 4096 + wlds], aptr[2] + kt);
    __builtin_amdgcn_s_barrier();
    asm volatile("s_waitcnt lgkmcnt(0)" ::: "memory");
    __builtin_amdgcn_s_setprio(1);
#pragma unroll
    for (int mi = 0; mi < 4; ++mi)
#pragma unroll
      for (int ni = 0; ni < NIH; ++ni)
#pragma unroll
        for (int ks = 0; ks < 2; ++ks)
          acc[4 + mi][ni] = __builtin_amdgcn_mfma_f32_16x16x32_bf16(af[mi][ks], bf[0][ni][ks], acc[4 + mi][ni], 0, 0, 0);
    __builtin_amdgcn_s_setprio(0);
    __builtin_amdgcn_s_barrier();

    // ---- phase 4: (mh1, nh1); stage next A1,A3; vmcnt(2) ----
    gload16(&lds[nb + 1 * 4096 + wlds], aptr[1] + kt);
    gload16(&lds[nb + 3 * 4096 + wlds], aptr[3] + kt);
    __builtin_amdgcn_s_barrier();
    __builtin_amdgcn_s_setprio(1);
#pragma unroll
    for (int mi = 0; mi < 4; ++mi)
#pragma unroll
      for (int ni = 0; ni < NIH; ++ni)
#pragma unroll
        for (int ks = 0; ks < 2; ++ks)
          acc[4 + mi][NIH + ni] = __builtin_amdgcn_mfma_f32_16x16x32_bf16(af[mi][ks], bf[1][ni][ks], acc[4 + mi][NIH + ni], 0, 0, 0);
    __builtin_amdgcn_s_setprio(0);
    asm volatile("s_waitcnt vmcnt(2)" ::: "memory");
    __builtin_amdgcn_s_barrier();
  }

  // epilogue: C/D layout col=lane&15, row=(lane>>4)*4+r
  const int m0 = bm * 256 + wr * 128 + hi * 4;
  const int n0 = bn * BN + wc * (BN / 4) + lr;
#pragma unroll
  for (int j = 0; j < 2 * NIH; ++j) {
    const int n = n0 + j * 16;
    const float bv = bias[n];
#pragma unroll
    for (int i = 0; i < 8; ++i) {
      f32x4 v = acc[i][j];
#pragma unroll
      for (int r = 0; r < 4; ++r) {
        const int m = m0 + i * 16 + r;
        float x = v[r] + bv;
        if (MODE == 1) {
          ((short*)Cv)[(size_t)m * N + n] = f2bf(gelu_tanh(x));
        } else {
          ((float*)Cv)[(size_t)m * N + n] = x;
        }
      }
    }
  }
}

extern "C" void kernel_launch(void* const* d_in, const int* in_sizes, int n_in,
                              void* d_out, int out_size, void* d_ws, size_t ws_size,
                              hipStream_t stream) {
  const int* idx = (const int*)d_in[0];
  const float* cb = (const float*)d_in[1];
  const float* W1 = (const float*)d_in[2];
  const float* b1 = (const float*)d_in[3];
  const float* W2 = (const float*)d_in[4];
  const float* b2 = (const float*)d_in[5];
  float* out = (float*)d_out;

  const int Mtot = 32 * 576;  // 18432

  // ws: Aq 40MB | W1T 8MB | W2T 8MB | h chunk
  char* ws = (char*)d_ws;
  short* aq = (short*)(ws);
  short* w1t = (short*)(ws + (size_t)40 * 1024 * 1024);
  short* w2t = (short*)(ws + (size_t)48 * 1024 * 1024);
  short* h = (short*)(ws + (size_t)56 * 1024 * 1024);

  gather_cvt<<<Mtot / 2, 256, 0, stream>>>(cb, idx, aq);
  cvt_T<<<2048, 256, 0, stream>>>(W1, w1t, 1024, 4096);  // -> [4096][1024]
  cvt_T<<<2048, 256, 0, stream>>>(W2, w2t, 4096, 1024);  // -> [1024][4096]

  size_t avail = (ws_size > (size_t)56 * 1024 * 1024) ? ws_size - (size_t)56 * 1024 * 1024 : 0;
  int nc = 1;
  while (nc < 8 && (size_t)(Mtot / nc) * 8192 > avail) nc <<= 1;
  const int Mc = Mtot / nc;  // multiple of 256 for nc in {1,2,4,8}

  for (int c = 0; c < nc; ++c) {
    gemm8p<1, 1024, 4096, 256><<<(Mc / 256) * 16, 512, 0, stream>>>(
        aq + (size_t)c * Mc * 1024, w1t, b1, (void*)h);
    gemm8p<2, 4096, 1024, 128><<<(Mc / 256) * 8, 512, 0, stream>>>(
        h, w2t, b2, (void*)(out + (size_t)c * Mc * 1024));
  }
}

// Round 4
// 492.844 us; speedup vs baseline: 1.0437x; 1.0437x over previous
//
#include <hip/hip_runtime.h>
#include <stdint.h>

typedef __attribute__((ext_vector_type(8))) short s16x8;
typedef __attribute__((ext_vector_type(4))) float f32x4;

__device__ __forceinline__ short f2bf(float x) {
  uint32_t u = __builtin_bit_cast(uint32_t, x);
  u += 0x7FFFu + ((u >> 16) & 1u);  // RNE
  return (short)(u >> 16);
}

__device__ __forceinline__ void gload16(void* l, const void* g) {
  __builtin_amdgcn_global_load_lds(
      (const __attribute__((address_space(1))) void*)g,
      (__attribute__((address_space(3))) void*)l, 16, 0, 0);
}

__device__ __forceinline__ float gelu_tanh(float x) {
  float u = 0.7978845608028654f * (x + 0.044715f * x * x * x);
  float e = __expf(2.0f * u);
  return x - x / (e + 1.0f);
}

// Aq[m][0:1024] = bf16(codebook[idx[m]][:])  -- gather + convert, 2 rows/block
__global__ void gather_cvt(const float* __restrict__ cb, const int* __restrict__ idx,
                           short* __restrict__ out) {
  int m = blockIdx.x * 2 + (threadIdx.x >> 7);
  int c = (threadIdx.x & 127) * 8;
  const float* s = cb + (size_t)idx[m] * 1024 + c;
  s16x8 o;
#pragma unroll
  for (int j = 0; j < 8; ++j) o[j] = f2bf(s[j]);
  *(s16x8*)(out + (size_t)m * 1024 + c) = o;
}

// in [K][N] fp32 -> out [N][K] bf16
__global__ void cvt_T(const float* __restrict__ in, short* __restrict__ out, int K, int N) {
  int Kb = K >> 3;
  int t = blockIdx.x * 256 + threadIdx.x;
  if (t >= N * Kb) return;
  int n = t / Kb;
  int k8 = (t - n * Kb) * 8;
  const float* s = in + (size_t)k8 * N + n;
  s16x8 o;
#pragma unroll
  for (int j = 0; j < 8; ++j) o[j] = f2bf(s[(size_t)j * N]);
  *(s16x8*)(out + (size_t)n * K + k8) = o;
}

// ---------------------------------------------------------------------------
// 4-phase 256xBN x64 bf16 GEMM, 8 waves (2M x 4N), double-buffered LDS,
// counted vmcnt, XOR-swizzled LDS (zero bank conflicts), XCD-chunked
// ROW-MAJOR tile order (bm major): consecutive blocks share the A-panel
// (L2 hit); small B streams via L3. (Column-major regressed: A=147MB is the
// big operand here -> 611MB HBM refetch, round-3 post-mortem.)
// MODE 1: epilogue bias+GELU -> bf16. MODE 2: epilogue bias -> fp32.
// ---------------------------------------------------------------------------
template <int MODE, int K, int N, int BN>
__global__ __launch_bounds__(512, 2) void gemm8p(
    const short* __restrict__ A, const short* __restrict__ Bt,
    const float* __restrict__ bias, void* __restrict__ Cv) {
  constexpr int NIH = BN / 128;        // n-frags per phase-half per wave
  constexpr int RB = BN / 64;          // B staging rounds per K-tile
  constexpr int ATS = 16384;           // A tile shorts (256*64)
  constexpr int LDSH = (256 + BN) * 64;
  __shared__ short lds[2 * LDSH];

  constexpr int NBN = N / BN;
  const int nwg = gridDim.x;
  int swz = blockIdx.x;
  swz = (swz & 7) * (nwg >> 3) + (swz >> 3);  // XCD swizzle (nwg % 8 == 0)
  const int bm = swz / NBN, bn = swz - (swz / NBN) * NBN;  // row-major

  const int tid = threadIdx.x;
  const int wid = tid >> 6, lane = tid & 63;
  const int wr = wid >> 2, wc = wid & 3;  // per-wave C: 128 x BN/4
  const int lr = lane & 15, hi = lane >> 4;

  // staging: round = 64 rows (8KB); thread -> row (tid>>3), phys slot tid&7,
  // fetch logical slot (tid&7)^(row&7)  (inverse swizzle on the source side)
  const int sl = (tid & 7) ^ ((tid >> 3) & 7);
  const short* aptr[4];
  const short* bptr[RB];
#pragma unroll
  for (int r = 0; r < 4; ++r)
    aptr[r] = A + (long)(bm * 256 + r * 64 + (tid >> 3)) * K + sl * 8;
#pragma unroll
  for (int r = 0; r < RB; ++r)
    bptr[r] = Bt + (long)(bn * BN + r * 64 + (tid >> 3)) * K + sl * 8;
  const int wlds = wid * 512;

  const int aRB = (wr * 128 + lr) * 64;
  const int bRB = ATS + (wc * (BN / 4) + lr) * 64;
  const int sk0 = ((0 + hi) ^ (lr & 7)) * 8;
  const int sk1 = ((4 + hi) ^ (lr & 7)) * 8;

  f32x4 acc[8][2 * NIH] = {};
  s16x8 af[4][2], bf[2][NIH][2];

  constexpr int NT = K >> 6;

  // prologue: tile 0 -> buf0; order B0..B(RB-1), A0, A2, A1, A3
#pragma unroll
  for (int r = 0; r < RB; ++r) gload16(&lds[ATS + r * 4096 + wlds], bptr[r]);
  gload16(&lds[0 * 4096 + wlds], aptr[0]);
  gload16(&lds[2 * 4096 + wlds], aptr[2]);
  gload16(&lds[1 * 4096 + wlds], aptr[1]);
  gload16(&lds[3 * 4096 + wlds], aptr[3]);
  asm volatile("s_waitcnt vmcnt(2)" ::: "memory");
  __builtin_amdgcn_s_barrier();

  for (int t = 0; t < NT; ++t) {
    const int cb = (t & 1) * LDSH;
    const int nb = LDSH - cb;
    const int kt = ((t + 1 < NT) ? (t + 1) : 0) << 6;

    // ---- phase 1: (mh0, nh0); stage next B[0..RB/2) ----
#pragma unroll
    for (int mi = 0; mi < 4; ++mi) {
      af[mi][0] = *(const s16x8*)&lds[cb + aRB + mi * 1024 + sk0];
      af[mi][1] = *(const s16x8*)&lds[cb + aRB + mi * 1024 + sk1];
    }
#pragma unroll
    for (int ni = 0; ni < NIH; ++ni) {
      bf[0][ni][0] = *(const s16x8*)&lds[cb + bRB + ni * 1024 + sk0];
      bf[0][ni][1] = *(const s16x8*)&lds[cb + bRB + ni * 1024 + sk1];
    }
#pragma unroll
    for (int r = 0; r < RB / 2; ++r)
      gload16(&lds[nb + ATS + r * 4096 + wlds], bptr[r] + kt);
    __builtin_amdgcn_s_barrier();
    asm volatile("s_waitcnt lgkmcnt(0)" ::: "memory");
    __builtin_amdgcn_s_setprio(1);
#pragma unroll
    for (int mi = 0; mi < 4; ++mi)
#pragma unroll
      for (int ni = 0; ni < NIH; ++ni)
#pragma unroll
        for (int ks = 0; ks < 2; ++ks)
          acc[mi][ni] = __builtin_amdgcn_mfma_f32_16x16x32_bf16(af[mi][ks], bf[0][ni][ks], acc[mi][ni], 0, 0, 0);
    __builtin_amdgcn_s_setprio(0);
    __builtin_amdgcn_s_barrier();

    // ---- phase 2: (mh0, nh1); stage next B[RB/2..RB) ----
#pragma unroll
    for (int ni = 0; ni < NIH; ++ni) {
      bf[1][ni][0] = *(const s16x8*)&lds[cb + bRB + (NIH + ni) * 1024 + sk0];
      bf[1][ni][1] = *(const s16x8*)&lds[cb + bRB + (NIH + ni) * 1024 + sk1];
    }
#pragma unroll
    for (int r = RB / 2; r < RB; ++r)
      gload16(&lds[nb + ATS + r * 4096 + wlds], bptr[r] + kt);
    __builtin_amdgcn_s_barrier();
    asm volatile("s_waitcnt lgkmcnt(0)" ::: "memory");
    __builtin_amdgcn_s_setprio(1);
#pragma unroll
    for (int mi = 0; mi < 4; ++mi)
#pragma unroll
      for (int ni = 0; ni < NIH; ++ni)
#pragma unroll
        for (int ks = 0; ks < 2; ++ks)
          acc[mi][NIH + ni] = __builtin_amdgcn_mfma_f32_16x16x32_bf16(af[mi][ks], bf[1][ni][ks], acc[mi][NIH + ni], 0, 0, 0);
    __builtin_amdgcn_s_setprio(0);
    if constexpr (RB == 4) asm volatile("s_waitcnt vmcnt(4)" ::: "memory");
    else                   asm volatile("s_waitcnt vmcnt(2)" ::: "memory");
    __builtin_amdgcn_s_barrier();

    // ---- phase 3: (mh1, nh0); stage next A0,A2 ----
#pragma unroll
    for (int mi = 0; mi < 4; ++mi) {
      af[mi][0] = *(const s16x8*)&lds[cb + aRB + 4096 + mi * 1024 + sk0];
      af[mi][1] = *(const s16x8*)&lds[cb + aRB + 4096 + mi * 1024 + sk1];
    }
    gload16(&lds[nb + 0 * 4096 + wlds], aptr[0] + kt);
    gload16(&lds[nb + 2 * 4096 + wlds], aptr[2] + kt);
    __builtin_amdgcn_s_barrier();
    asm volatile("s_waitcnt lgkmcnt(0)" ::: "memory");
    __builtin_amdgcn_s_setprio(1);
#pragma unroll
    for (int mi = 0; mi < 4; ++mi)
#pragma unroll
      for (int ni = 0; ni < NIH; ++ni)
#pragma unroll
        for (int ks = 0; ks < 2; ++ks)
          acc[4 + mi][ni] = __builtin_amdgcn_mfma_f32_16x16x32_bf16(af[mi][ks], bf[0][ni][ks], acc[4 + mi][ni], 0, 0, 0);
    __builtin_amdgcn_s_setprio(0);
    __builtin_amdgcn_s_barrier();

    // ---- phase 4: (mh1, nh1); stage next A1,A3; vmcnt(2) ----
    gload16(&lds[nb + 1 * 4096 + wlds], aptr[1] + kt);
    gload16(&lds[nb + 3 * 4096 + wlds], aptr[3] + kt);
    __builtin_amdgcn_s_barrier();
    __builtin_amdgcn_s_setprio(1);
#pragma unroll
    for (int mi = 0; mi < 4; ++mi)
#pragma unroll
      for (int ni = 0; ni < NIH; ++ni)
#pragma unroll
        for (int ks = 0; ks < 2; ++ks)
          acc[4 + mi][NIH + ni] = __builtin_amdgcn_mfma_f32_16x16x32_bf16(af[mi][ks], bf[1][ni][ks], acc[4 + mi][NIH + ni], 0, 0, 0);
    __builtin_amdgcn_s_setprio(0);
    asm volatile("s_waitcnt vmcnt(2)" ::: "memory");
    __builtin_amdgcn_s_barrier();
  }

  // epilogue: C/D layout col=lane&15, row=(lane>>4)*4+r
  const int m0 = bm * 256 + wr * 128 + hi * 4;
  const int n0 = bn * BN + wc * (BN / 4) + lr;
#pragma unroll
  for (int j = 0; j < 2 * NIH; ++j) {
    const int n = n0 + j * 16;
    const float bv = bias[n];
#pragma unroll
    for (int i = 0; i < 8; ++i) {
      f32x4 v = acc[i][j];
#pragma unroll
      for (int r = 0; r < 4; ++r) {
        const int m = m0 + i * 16 + r;
        float x = v[r] + bv;
        if (MODE == 1) {
          ((short*)Cv)[(size_t)m * N + n] = f2bf(gelu_tanh(x));
        } else {
          ((float*)Cv)[(size_t)m * N + n] = x;
        }
      }
    }
  }
}

extern "C" void kernel_launch(void* const* d_in, const int* in_sizes, int n_in,
                              void* d_out, int out_size, void* d_ws, size_t ws_size,
                              hipStream_t stream) {
  const int* idx = (const int*)d_in[0];
  const float* cb = (const float*)d_in[1];
  const float* W1 = (const float*)d_in[2];
  const float* b1 = (const float*)d_in[3];
  const float* W2 = (const float*)d_in[4];
  const float* b2 = (const float*)d_in[5];
  float* out = (float*)d_out;

  const int Mtot = 32 * 576;  // 18432

  // ws: Aq 40MB | W1T 8MB | W2T 8MB | h chunk
  char* ws = (char*)d_ws;
  short* aq = (short*)(ws);
  short* w1t = (short*)(ws + (size_t)40 * 1024 * 1024);
  short* w2t = (short*)(ws + (size_t)48 * 1024 * 1024);
  short* h = (short*)(ws + (size_t)56 * 1024 * 1024);

  gather_cvt<<<Mtot / 2, 256, 0, stream>>>(cb, idx, aq);
  cvt_T<<<2048, 256, 0, stream>>>(W1, w1t, 1024, 4096);  // -> [4096][1024]
  cvt_T<<<2048, 256, 0, stream>>>(W2, w2t, 4096, 1024);  // -> [1024][4096]

  size_t avail = (ws_size > (size_t)56 * 1024 * 1024) ? ws_size - (size_t)56 * 1024 * 1024 : 0;
  int nc = 1;
  while (nc < 8 && (size_t)(Mtot / nc) * 8192 > avail) nc <<= 1;
  const int Mc = Mtot / nc;  // multiple of 256 for nc in {1,2,4,8}

  for (int c = 0; c < nc; ++c) {
    gemm8p<1, 1024, 4096, 256><<<(Mc / 256) * 16, 512, 0, stream>>>(
        aq + (size_t)c * Mc * 1024, w1t, b1, (void*)h);
    gemm8p<2, 4096, 1024, 128><<<(Mc / 256) * 8, 512, 0, stream>>>(
        h, w2t, b2, (void*)(out + (size_t)c * Mc * 1024));
  }
}

// Round 5
// 395.917 us; speedup vs baseline: 1.2993x; 1.2448x over previous
//
#include <hip/hip_runtime.h>
#include <stdint.h>

typedef __attribute__((ext_vector_type(8))) short s16x8;
typedef __attribute__((ext_vector_type(4))) float f32x4;

__device__ __forceinline__ short f2bf(float x) {
  uint32_t u = __builtin_bit_cast(uint32_t, x);
  u += 0x7FFFu + ((u >> 16) & 1u);  // RNE
  return (short)(u >> 16);
}

__device__ __forceinline__ void gload16(void* l, const void* g) {
  __builtin_amdgcn_global_load_lds(
      (const __attribute__((address_space(1))) void*)g,
      (__attribute__((address_space(3))) void*)l, 16, 0, 0);
}

__device__ __forceinline__ float gelu_tanh(float x) {
  float u = 0.7978845608028654f * (x + 0.044715f * x * x * x);
  float e = __expf(2.0f * u);
  return x - x / (e + 1.0f);
}

// Aq[m][:] = bf16(codebook[idx[m]][:])
__global__ void gather_cvt(const float* __restrict__ cb, const int* __restrict__ idx,
                           short* __restrict__ out) {
  int m = blockIdx.x * 2 + (threadIdx.x >> 7);
  int c = (threadIdx.x & 127) * 8;
  const float* s = cb + (size_t)idx[m] * 1024 + c;
  s16x8 o;
#pragma unroll
  for (int j = 0; j < 8; ++j) o[j] = f2bf(s[j]);
  *(s16x8*)(out + (size_t)m * 1024 + c) = o;
}

// in [K][N] fp32 -> out [N][K] bf16
__global__ void cvt_T(const float* __restrict__ in, short* __restrict__ out, int K, int N) {
  int Kb = K >> 3;
  int t = blockIdx.x * 256 + threadIdx.x;
  if (t >= N * Kb) return;
  int n = t / Kb;
  int k8 = (t - n * Kb) * 8;
  const float* s = in + (size_t)k8 * N + n;
  s16x8 o;
#pragma unroll
  for (int j = 0; j < 8; ++j) o[j] = f2bf(s[(size_t)j * N]);
  *(s16x8*)(out + (size_t)n * K + k8) = o;
}

// ---------------------------------------------------------------------------
// 4-phase 288x256x64 bf16 GEMM, 8 waves (2M x 4N, per-wave 144x64 = 9x4
// frags), double-buffered LDS, counted vmcnt (never 0 in loop), XOR-swizzled
// LDS, XCD-chunked row-major tiles.
// BM=288: 18432/288=64 m-tiles -> GEMM2 grid 256 = exactly 1 round (100%),
// GEMM1 grid 1024 = exactly 4 rounds (100%). A-tile = 4 full 64-row staging
// rounds + one 32-row round (waves 0-3 real, waves 4-7 -> LDS scratch so
// per-wave vmcnt counts stay uniform).
// MODE 1: epilogue bias+GELU -> bf16. MODE 2: epilogue bias -> fp32.
// ---------------------------------------------------------------------------
template <int MODE, int K, int N>
__global__ __launch_bounds__(512, 2) void gemm8p(
    const short* __restrict__ A, const short* __restrict__ Bt,
    const float* __restrict__ bias, void* __restrict__ Cv) {
  constexpr int BM = 288, BN = 256;
  constexpr int ATS = BM * 64;          // 18432 shorts
  constexpr int LDSH = (BM + BN) * 64;  // 34816 shorts
  __shared__ short lds[2 * LDSH + 2048];  // + 4KB scratch = 143360 B

  constexpr int NBN = N / BN;
  const int nwg = gridDim.x;
  int swz = blockIdx.x;
  swz = (swz & 7) * (nwg >> 3) + (swz >> 3);  // XCD swizzle (nwg % 8 == 0)
  const int bm = swz / NBN, bn = swz - (swz / NBN) * NBN;  // row-major

  const int tid = threadIdx.x;
  const int wid = tid >> 6, lane = tid & 63;
  const int wr = wid >> 2, wc = wid & 3;  // per-wave C: 144 x 64
  const int lr = lane & 15, hi = lane >> 4;

  // staging: round = 64 rows (8KB); thread -> row (tid>>3), phys slot tid&7,
  // source fetches logical slot (tid&7)^(row&7) (inverse swizzle on source)
  const int sl = (tid & 7) ^ ((tid >> 3) & 7);
  const long rstep = (long)64 * K;
  const short* aptr0 = A + (long)(bm * BM + (tid >> 3)) * K + sl * 8;
  const short* aptr4 = A + (long)(bm * BM + 256 + ((tid >> 3) & 31)) * K + sl * 8;
  const short* bptr0 = Bt + (long)(bn * BN + (tid >> 3)) * K + sl * 8;
  const int wlds = wid * 512;  // wave's 1KB block within a round
  const int a4rel = (wid < 4) ? (16384 + wid * 512) : -1;  // -1 -> scratch

  // ds_read bases; slot XOR-swizzled by row&7 (= lr&7)
  const int aRB = (wr * 144 + lr) * 64;
  const int bRB = ATS + (wc * 64 + lr) * 64;
  const int sk0 = ((0 + hi) ^ (lr & 7)) * 8;
  const int sk1 = ((4 + hi) ^ (lr & 7)) * 8;

  f32x4 acc[9][4] = {};
  s16x8 af[5][2], bf[2][2][2];

  constexpr int NT = K >> 6;

  // prologue: tile 0 -> buf0. Order: B0..B3, A0,A2,A3, A1,A4 (A1,A4 newest)
#pragma unroll
  for (int r = 0; r < 4; ++r) gload16(&lds[ATS + r * 4096 + wlds], bptr0 + r * rstep);
  gload16(&lds[0 * 4096 + wlds], aptr0 + 0 * rstep);
  gload16(&lds[2 * 4096 + wlds], aptr0 + 2 * rstep);
  gload16(&lds[3 * 4096 + wlds], aptr0 + 3 * rstep);
  gload16(&lds[1 * 4096 + wlds], aptr0 + 1 * rstep);
  gload16((a4rel >= 0) ? &lds[a4rel] : &lds[2 * LDSH + (wid & 3) * 512], aptr4);
  asm volatile("s_waitcnt vmcnt(2)" ::: "memory");
  __builtin_amdgcn_s_barrier();

  for (int t = 0; t < NT; ++t) {
    const int cb = (t & 1) * LDSH;
    const int nb = LDSH - cb;
    const int kt = ((t + 1 < NT) ? (t + 1) : 0) << 6;

    // ---- phase 1: m-frags 0-3 x n-frags 0-1; stage next B0,B1 ----
#pragma unroll
    for (int mi = 0; mi < 4; ++mi) {
      af[mi][0] = *(const s16x8*)&lds[cb + aRB + mi * 1024 + sk0];
      af[mi][1] = *(const s16x8*)&lds[cb + aRB + mi * 1024 + sk1];
    }
#pragma unroll
    for (int ni = 0; ni < 2; ++ni) {
      bf[0][ni][0] = *(const s16x8*)&lds[cb + bRB + ni * 1024 + sk0];
      bf[0][ni][1] = *(const s16x8*)&lds[cb + bRB + ni * 1024 + sk1];
    }
    gload16(&lds[nb + ATS + 0 * 4096 + wlds], bptr0 + 0 * rstep + kt);
    gload16(&lds[nb + ATS + 1 * 4096 + wlds], bptr0 + 1 * rstep + kt);
    __builtin_amdgcn_s_barrier();
    asm volatile("s_waitcnt lgkmcnt(0)" ::: "memory");
    __builtin_amdgcn_s_setprio(1);
#pragma unroll
    for (int mi = 0; mi < 4; ++mi)
#pragma unroll
      for (int ni = 0; ni < 2; ++ni)
#pragma unroll
        for (int ks = 0; ks < 2; ++ks)
          acc[mi][ni] = __builtin_amdgcn_mfma_f32_16x16x32_bf16(af[mi][ks], bf[0][ni][ks], acc[mi][ni], 0, 0, 0);
    __builtin_amdgcn_s_setprio(0);
    __builtin_amdgcn_s_barrier();

    // ---- phase 2: m-frags 0-3 x n-frags 2-3; stage next B2,B3; vmcnt(4) ----
#pragma unroll
    for (int ni = 0; ni < 2; ++ni) {
      bf[1][ni][0] = *(const s16x8*)&lds[cb + bRB + (2 + ni) * 1024 + sk0];
      bf[1][ni][1] = *(const s16x8*)&lds[cb + bRB + (2 + ni) * 1024 + sk1];
    }
    gload16(&lds[nb + ATS + 2 * 4096 + wlds], bptr0 + 2 * rstep + kt);
    gload16(&lds[nb + ATS + 3 * 4096 + wlds], bptr0 + 3 * rstep + kt);
    __builtin_amdgcn_s_barrier();
    asm volatile("s_waitcnt lgkmcnt(0)" ::: "memory");
    __builtin_amdgcn_s_setprio(1);
#pragma unroll
    for (int mi = 0; mi < 4; ++mi)
#pragma unroll
      for (int ni = 0; ni < 2; ++ni)
#pragma unroll
        for (int ks = 0; ks < 2; ++ks)
          acc[mi][2 + ni] = __builtin_amdgcn_mfma_f32_16x16x32_bf16(af[mi][ks], bf[1][ni][ks], acc[mi][2 + ni], 0, 0, 0);
    __builtin_amdgcn_s_setprio(0);
    asm volatile("s_waitcnt vmcnt(4)" ::: "memory");  // cur A1,A4 landed
    __builtin_amdgcn_s_barrier();

    // ---- phase 3: m-frags 4-8 x n-frags 0-1; stage next A0,A2,A3 ----
#pragma unroll
    for (int mi = 0; mi < 5; ++mi) {
      af[mi][0] = *(const s16x8*)&lds[cb + aRB + (4 + mi) * 1024 + sk0];
      af[mi][1] = *(const s16x8*)&lds[cb + aRB + (4 + mi) * 1024 + sk1];
    }
    gload16(&lds[nb + 0 * 4096 + wlds], aptr0 + 0 * rstep + kt);
    gload16(&lds[nb + 2 * 4096 + wlds], aptr0 + 2 * rstep + kt);
    gload16(&lds[nb + 3 * 4096 + wlds], aptr0 + 3 * rstep + kt);
    __builtin_amdgcn_s_barrier();
    asm volatile("s_waitcnt lgkmcnt(0)" ::: "memory");
    __builtin_amdgcn_s_setprio(1);
#pragma unroll
    for (int mi = 0; mi < 5; ++mi)
#pragma unroll
      for (int ni = 0; ni < 2; ++ni)
#pragma unroll
        for (int ks = 0; ks < 2; ++ks)
          acc[4 + mi][ni] = __builtin_amdgcn_mfma_f32_16x16x32_bf16(af[mi][ks], bf[0][ni][ks], acc[4 + mi][ni], 0, 0, 0);
    __builtin_amdgcn_s_setprio(0);
    __builtin_amdgcn_s_barrier();

    // ---- phase 4: m-frags 4-8 x n-frags 2-3; stage next A1,A4; vmcnt(2) ----
    gload16(&lds[nb + 1 * 4096 + wlds], aptr0 + 1 * rstep + kt);
    gload16((a4rel >= 0) ? &lds[nb + a4rel] : &lds[2 * LDSH + (wid & 3) * 512], aptr4 + kt);
    __builtin_amdgcn_s_barrier();
    __builtin_amdgcn_s_setprio(1);
#pragma unroll
    for (int mi = 0; mi < 5; ++mi)
#pragma unroll
      for (int ni = 0; ni < 2; ++ni)
#pragma unroll
        for (int ks = 0; ks < 2; ++ks)
          acc[4 + mi][2 + ni] = __builtin_amdgcn_mfma_f32_16x16x32_bf16(af[mi][ks], bf[1][ni][ks], acc[4 + mi][2 + ni], 0, 0, 0);
    __builtin_amdgcn_s_setprio(0);
    asm volatile("s_waitcnt vmcnt(2)" ::: "memory");  // all but next A1,A4
    __builtin_amdgcn_s_barrier();
  }

  // epilogue: C/D layout col=lane&15, row=(lane>>4)*4+r
  const int m0 = bm * BM + wr * 144 + hi * 4;
  const int n0 = bn * BN + wc * 64 + lr;
#pragma unroll
  for (int j = 0; j < 4; ++j) {
    const int n = n0 + j * 16;
    const float bv = bias[n];
#pragma unroll
    for (int i = 0; i < 9; ++i) {
      f32x4 v = acc[i][j];
#pragma unroll
      for (int r = 0; r < 4; ++r) {
        const int m = m0 + i * 16 + r;
        float x = v[r] + bv;
        if (MODE == 1) {
          ((short*)Cv)[(size_t)m * N + n] = f2bf(gelu_tanh(x));
        } else {
          ((float*)Cv)[(size_t)m * N + n] = x;
        }
      }
    }
  }
}

extern "C" void kernel_launch(void* const* d_in, const int* in_sizes, int n_in,
                              void* d_out, int out_size, void* d_ws, size_t ws_size,
                              hipStream_t stream) {
  const int* idx = (const int*)d_in[0];
  const float* cb = (const float*)d_in[1];
  const float* W1 = (const float*)d_in[2];
  const float* b1 = (const float*)d_in[3];
  const float* W2 = (const float*)d_in[4];
  const float* b2 = (const float*)d_in[5];
  float* out = (float*)d_out;

  const int Mtot = 32 * 576;  // 18432 = 64 * 288

  // ws: Aq 40MB | W1T 8MB | W2T 8MB | h chunk
  char* ws = (char*)d_ws;
  short* aq = (short*)(ws);
  short* w1t = (short*)(ws + (size_t)40 * 1024 * 1024);
  short* w2t = (short*)(ws + (size_t)48 * 1024 * 1024);
  short* h = (short*)(ws + (size_t)56 * 1024 * 1024);

  gather_cvt<<<Mtot / 2, 256, 0, stream>>>(cb, idx, aq);
  cvt_T<<<2048, 256, 0, stream>>>(W1, w1t, 1024, 4096);  // -> [4096][1024]
  cvt_T<<<2048, 256, 0, stream>>>(W2, w2t, 4096, 1024);  // -> [1024][4096]

  size_t avail = (ws_size > (size_t)56 * 1024 * 1024) ? ws_size - (size_t)56 * 1024 * 1024 : 0;
  int nc = 1;
  while (nc < 8 && (size_t)(Mtot / nc) * 8192 > avail) nc <<= 1;
  const int Mc = Mtot / nc;  // Mc/288 integer for nc in {1,2,4,8}

  for (int c = 0; c < nc; ++c) {
    gemm8p<1, 1024, 4096><<<(Mc / 288) * 16, 512, 0, stream>>>(
        aq + (size_t)c * Mc * 1024, w1t, b1, (void*)h);
    gemm8p<2, 4096, 1024><<<(Mc / 288) * 4, 512, 0, stream>>>(
        h, w2t, b2, (void*)(out + (size_t)c * Mc * 1024));
  }
}